// Round 9
// baseline (108.150 us; speedup 1.0000x reference)
//
#include <hip/hip_runtime.h>
#include <stdint.h>
#include <math.h>

#define B_    4
#define HW    36864
#define NPIX  147456
#define C_V   10
#define C_F   64
#define C_D   16
#define C_ALL 90
#define HBINS 32768              // fine bins: key bits 30..16 (u16-packed, 2/word)
#define HWRD  16384              // u32 words per batch (2 bins per word)
#define CAP   1536               // bin-b* list capacity (expected ~150)
#define INV   0xFFFFFFFFu

// ---- workspace layout (bytes), 16B-aligned ----
#define OFF_HIST 0u              // 4*HWRD*4 = 262144 (zeroed by k_zero)
#define OFF_KEY  262144u         // NPIX*4 = 589824
#define OFF_G    851968u         // NPIX
#define OFF_SELC 999424u         // NPIX (byte per pixel, u32 per 4-px group)

__device__ __forceinline__ uint32_t costOf(uint32_t g) {
    return g == 0u ? 10u : (g == 1u ? 5u : 2u);
}

// budget_per_sample = float32(budget / B); usage,c exact ints ->
// usage+c <= bps  <=>  usage+c <= floor(bps)
__device__ __forceinline__ uint32_t budgetInt(const int* bptr) {
    double bps = (double)bptr[0] / (double)B_;
    float f = (float)bps;
    return (uint32_t)floorf(f);
}

// compare-exchange keeping max in x (descending)
#define CE(x, y) { uint64_t _mn = (x) < (y) ? (x) : (y); \
                   uint64_t _mx = (x) < (y) ? (y) : (x); (x) = _mx; (y) = _mn; }

// K0: zero u16-packed histogram (256 KB)
__global__ void k_zero(uint4* __restrict__ w4) {
    uint32_t i = blockIdx.x * blockDim.x + threadIdx.x;   // [0, 16384)
    w4[i] = make_uint4(0u, 0u, 0u, 0u);
}

// K1: per-pixel best utility / group / sortable key + u16-packed fine hist.
__global__ void k_prep(const float* __restrict__ util, uint4* __restrict__ key4,
                       uint32_t* __restrict__ g4, uint32_t* __restrict__ hist) {
    int t = blockIdx.x * blockDim.x + threadIdx.x;   // [0, NPIX/4)
    if (t >= NPIX / 4) return;
    const float4* u4 = (const float4*)util + (size_t)t * 3;
    float4 a = u4[0], b4 = u4[1], c4 = u4[2];
    float u[4][3] = { {a.x, a.y, a.z}, {a.w, b4.x, b4.y},
                      {b4.z, b4.w, c4.x}, {c4.y, c4.z, c4.w} };
    uint32_t kk[4]; uint32_t gpack = 0;
    #pragma unroll
    for (int p = 0; p < 4; ++p) {
        float best = u[p][0]; uint32_t g = 0;
        if (u[p][1] > best) { best = u[p][1]; g = 1; }   // strict > = first max
        if (u[p][2] > best) { best = u[p][2]; g = 2; }
        kk[p] = (best > 0.0f) ? (__float_as_uint(best) | 0x80000000u) : 0u;
        gpack |= g << (8 * p);
    }
    key4[t] = make_uint4(kk[0], kk[1], kk[2], kk[3]);
    g4[t] = gpack;
    int b = (t * 4) / HW;                     // HW % 4 == 0
    #pragma unroll
    for (int p = 0; p < 4; ++p)
        if (kk[p]) {
            uint32_t bin = (kk[p] >> 16) & 32767u;
            uint32_t c = costOf((gpack >> (8 * p)) & 3u);
            atomicAdd(&hist[(size_t)b * HWRD + (bin >> 1)], c << (16u * (bin & 1u)));
        }
}

// K2: self-contained per-batch selection + output-map emission.
// All global loads issued UP FRONT (22 vmem/thread) -> one latency window.
// A: u16-hist descending cumsum -> b2/usage.  B: classify prefetched keys ->
// LDS bin-b* list + reg tail top-1 cost-5 / top-4 cost-2.  C: rank-sort +
// serial greedy + exact <=5-pick tail replay into LDS bitmap.
// D: selc byte-map + sel_idx float output for all pixels.
__global__ __launch_bounds__(1024) void k_sel(const uint32_t* __restrict__ key,
                                              const uint8_t* __restrict__ g,
                                              const uint32_t* __restrict__ hist,
                                              const int* __restrict__ budget_ptr,
                                              uint32_t* __restrict__ selc,
                                              float* __restrict__ outSel) {
    int b = blockIdx.x;
    int t = threadIdx.x;
    int lane = t & 63, wv = t >> 6;
    uint32_t budget = budgetInt(budget_ptr);

    __shared__ uint32_t wsum[16];
    __shared__ uint32_t sh_b2, sh_usage, sh_n;
    __shared__ uint32_t selbit[1152];            // 36864-pixel bitmap
    __shared__ uint64_t e[CAP];
    __shared__ uint64_t s[CAP];
    __shared__ uint64_t red5[16];
    __shared__ uint64_t red2[16][4];

    selbit[t] = 0u;
    if (t < 128) selbit[1024 + t] = 0u;
    if (t == 0) { sh_b2 = INV; sh_usage = 0u; sh_n = 0u; }

    // ---- issue ALL global loads up front ----
    const uint32_t* hb = hist + (size_t)b * HWRD;
    const uint4* h4 = (const uint4*)(hb + (16368 - 16 * t));  // words, descending chunks
    uint4 hv[4];
    #pragma unroll
    for (int j = 0; j < 4; ++j) hv[j] = h4[j];
    const uint4*    k4  = (const uint4*)(key + (size_t)b * HW);
    const uint32_t* g4p = (const uint32_t*)(g + (size_t)b * HW);
    uint4 kk[9]; uint32_t gp[9];
    #pragma unroll
    for (int it = 0; it < 9; ++it) {
        int gi = t + it * 1024;                  // [0, 9216)
        kk[it] = k4[gi];
        gp[it] = g4p[gi];
    }

    // ---- Phase A: descending cumsum over 32768 bins (u16 pairs) ----
    // thread t covers bins [32736-32t .. 32767-32t]
    uint32_t cs = 0;
    #pragma unroll
    for (int j = 0; j < 4; ++j)
        cs += (hv[j].x & 0xFFFFu) + (hv[j].x >> 16) + (hv[j].y & 0xFFFFu) + (hv[j].y >> 16)
            + (hv[j].z & 0xFFFFu) + (hv[j].z >> 16) + (hv[j].w & 0xFFFFu) + (hv[j].w >> 16);
    uint32_t v = cs;
    #pragma unroll
    for (int off = 1; off < 64; off <<= 1) {     // wave inclusive scan
        uint32_t o = __shfl_up(v, off);
        if (lane >= off) v += o;
    }
    if (lane == 63) wsum[wv] = v;
    __syncthreads();                              // also covers selbit/sh_* init
    if (t < 16) {
        uint32_t w = wsum[t];
        #pragma unroll
        for (int off = 1; off < 16; off <<= 1) {
            uint32_t o = __shfl_up(w, off);
            if (t >= off) w += o;
        }
        wsum[t] = w;
    }
    __syncthreads();
    uint32_t incl = v + (wv ? wsum[wv - 1] : 0u);
    uint32_t excl = incl - cs;
    if (excl <= budget && incl > budget) {        // exactly one finder thread
        uint32_t base = 32736u - 32u * (uint32_t)t;
        uint32_t cum = excl, fb2 = INV, fus = 0;
        // walk bins descending: word wi holds bins base+2wi (lo), base+2wi+1 (hi)
        #define STEPW(W, wi) { \
            uint32_t _hi = (W) >> 16, _lo = (W) & 0xFFFFu; \
            if (fb2 == INV) { if (cum + _hi > budget) { fb2 = base + 2u*(wi) + 1u; fus = cum; } else cum += _hi; } \
            if (fb2 == INV) { if (cum + _lo > budget) { fb2 = base + 2u*(wi);      fus = cum; } else cum += _lo; } }
        STEPW(hv[3].w, 15) STEPW(hv[3].z, 14) STEPW(hv[3].y, 13) STEPW(hv[3].x, 12)
        STEPW(hv[2].w, 11) STEPW(hv[2].z, 10) STEPW(hv[2].y,  9) STEPW(hv[2].x,  8)
        STEPW(hv[1].w,  7) STEPW(hv[1].z,  6) STEPW(hv[1].y,  5) STEPW(hv[1].x,  4)
        STEPW(hv[0].w,  3) STEPW(hv[0].z,  2) STEPW(hv[0].y,  1) STEPW(hv[0].x,  0)
        #undef STEPW
        sh_b2 = fb2; sh_usage = fus;              // fb2 != INV guaranteed (incl>budget)
    }
    __syncthreads();
    uint32_t b2 = sh_b2;                          // block-uniform

    if (b2 != INV) {                              // uniform branch: barriers inside OK
        // ---- Phase B: classify prefetched keys ----
        uint64_t m5 = 0, a0 = 0, a1 = 0, a2 = 0, a3 = 0;
        #pragma unroll
        for (int it = 0; it < 9; ++it) {
            int gi = t + it * 1024;
            uint32_t kv[4] = { kk[it].x, kk[it].y, kk[it].z, kk[it].w };
            #pragma unroll
            for (int p = 0; p < 4; ++p) {
                uint32_t k = kv[p];
                if (!k) continue;
                uint32_t bin = (k >> 16) & 32767u;
                uint32_t gg = (gp[it] >> (8 * p)) & 3u;
                uint32_t pix = (uint32_t)(gi * 4 + p);
                if (bin == b2) {
                    uint32_t idx = atomicAdd(&sh_n, 1u);    // LDS atomic
                    if (idx < CAP)   // asc key: (~k, pix) -> utility desc, pix asc
                        e[idx] = ((uint64_t)(~k) << 32) | ((uint64_t)pix << 2)
                               | (uint64_t)gg;
                } else if (bin < b2 && gg) {      // cost-10 never fits (r <= 9)
                    uint64_t m = ((uint64_t)k << 18)
                               | ((uint64_t)(65535u - pix) << 2) | (uint64_t)gg;
                    if (gg == 1u) { if (m > m5) m5 = m; }
                    else if (m > a3) {
                        if      (m > a0) { a3 = a2; a2 = a1; a1 = a0; a0 = m; }
                        else if (m > a1) { a3 = a2; a2 = a1; a1 = m; }
                        else if (m > a2) { a3 = a2; a2 = m; }
                        else             { a3 = m; }
                    }
                }
            }
        }
        #pragma unroll
        for (int off = 32; off; off >>= 1) {      // wave reduce tails
            uint64_t o5 = __shfl_down(m5, off);
            if (o5 > m5) m5 = o5;
            uint64_t b0 = __shfl_down(a0, off), b1 = __shfl_down(a1, off),
                     b2_ = __shfl_down(a2, off), b3 = __shfl_down(a3, off);
            CE(a0, b3); CE(a1, b2_); CE(a2, b1); CE(a3, b0);
            CE(a0, a2); CE(a1, a3); CE(a0, a1); CE(a2, a3);
        }
        if (lane == 0) {
            red5[wv] = m5;
            red2[wv][0] = a0; red2[wv][1] = a1; red2[wv][2] = a2; red2[wv][3] = a3;
        }
        __syncthreads();

        // ---- Phase C: rank-sort + serial greedy + tail replay ----
        int n = (int)(sh_n < (uint32_t)CAP ? sh_n : (uint32_t)CAP);
        for (int i = t; i < n; i += 1024) {       // rank sort (keys distinct)
            uint64_t ei = e[i];
            int rk = 0;
            for (int j = 0; j < n; ++j) rk += (e[j] < ei);
            s[rk] = ei;
        }
        __syncthreads();
        if (t == 0) {
            uint64_t g5 = 0, c0 = 0, c1 = 0, c2 = 0, c3 = 0;
            for (int wq = 0; wq < 16; ++wq) {     // merge 16 waves' candidates
                if (red5[wq] > g5) g5 = red5[wq];
                #pragma unroll
                for (int q = 0; q < 4; ++q) {
                    uint64_t m = red2[wq][q];
                    if (m > c3) {
                        if      (m > c0) { c3 = c2; c2 = c1; c1 = c0; c0 = m; }
                        else if (m > c1) { c3 = c2; c2 = c1; c1 = m; }
                        else if (m > c2) { c3 = c2; c2 = m; }
                        else             { c3 = m; }
                    }
                }
            }
            // serial greedy within bin b* (marks LDS bitmap)
            uint32_t usage = sh_usage;
            for (int i = 0; i < n; ++i) {
                uint64_t ei = s[i];
                uint32_t c = costOf((uint32_t)(ei & 3u));
                if (usage + c <= budget) {
                    usage += c;
                    uint32_t pix = (uint32_t)((ei >> 2) & 0xFFFFu);
                    selbit[pix >> 5] |= 1u << (pix & 31u);
                }
            }
            // exact <=5-pick tail replay below bin b*
            uint64_t c5[5] = { g5, c0, c1, c2, c3 };
            for (int i = 1; i < 5; ++i) {
                uint64_t x = c5[i]; int j = i;
                while (j > 0 && c5[j - 1] < x) { c5[j] = c5[j - 1]; --j; }
                c5[j] = x;
            }
            uint32_t r = budget - usage;          // provably <= 9
            for (int i = 0; i < 5; ++i) {
                uint64_t m = c5[i];
                if (!m) break;
                uint32_t c = costOf((uint32_t)(m & 3u));
                if (c <= r) {
                    r -= c;
                    uint32_t pix = 65535u - (uint32_t)((m >> 2) & 0xFFFFu);
                    selbit[pix >> 5] |= 1u << (pix & 31u);
                }
            }
        }
    }
    __syncthreads();

    // ---- Phase D: selc byte-map + sel_idx output ----
    uint32_t hl;
    if (b2 == INV) hl = 1u;                       // no crossing: all valid selected
    else { uint32_t bs = b2 + 32768u;
           hl = (bs >= 65535u) ? INV : ((bs + 1u) << 16); }
    #pragma unroll
    for (int it = 0; it < 9; ++it) {
        int gi = t + it * 1024;
        uint32_t kv[4] = { kk[it].x, kk[it].y, kk[it].z, kk[it].w };
        uint32_t bits = (selbit[gi >> 3] >> ((gi & 7) * 4)) & 0xFu;
        uint32_t sel = 0; float sf[4];
        #pragma unroll
        for (int p = 0; p < 4; ++p) {
            bool se = (kv[p] >= hl) || ((bits >> p) & 1u);
            uint32_t gq = (gp[it] >> (8 * p)) & 3u;
            sel |= (se ? gq : 0xFFu) << (8 * p);
            sf[p] = se ? (float)gq : -1.0f;
        }
        selc[(size_t)b * (HW / 4) + gi] = sel;
        ((float4*)outSel)[(size_t)b * (HW / 4) + gi] =
            make_float4(sf[0], sf[1], sf[2], sf[3]);
    }
}

// K3: masked sparse BEV from selc byte-map, float4-vectorized streaming.
__global__ __launch_bounds__(256) void k_sparse(const float* __restrict__ collab,
                                                const uint32_t* __restrict__ selc,
                                                float* __restrict__ out) {
    int tid = blockIdx.x * blockDim.x + threadIdx.x;   // [0, HW/4)
    int c = blockIdx.y, b = blockIdx.z;
    uint32_t cls = (c < C_V) ? 0u : ((c < C_V + C_F) ? 1u : 2u);
    uint32_t sel = selc[(size_t)b * (HW / 4) + tid];
    size_t co = ((size_t)(b * C_ALL + c)) * (HW / 4) + (size_t)tid;
    float4 v = ((const float4*)collab)[co];
    float4 o;
    o.x = (((sel      ) & 0xFFu) == cls) ? v.x : 0.0f;
    o.y = (((sel >>  8) & 0xFFu) == cls) ? v.y : 0.0f;
    o.z = (((sel >> 16) & 0xFFu) == cls) ? v.z : 0.0f;
    o.w = (((sel >> 24) & 0xFFu) == cls) ? v.w : 0.0f;
    ((float4*)out)[co] = o;
}

extern "C" void kernel_launch(void* const* d_in, const int* in_sizes, int n_in,
                              void* d_out, int out_size, void* d_ws, size_t ws_size,
                              hipStream_t stream) {
    (void)in_sizes; (void)n_in; (void)out_size; (void)ws_size;
    const float* collab = (const float*)d_in[0];
    const float* util   = (const float*)d_in[1];
    const int*   budget = (const int*)d_in[2];

    uint8_t*  ws   = (uint8_t*)d_ws;
    uint32_t* hist = (uint32_t*)(ws + OFF_HIST);
    uint32_t* key  = (uint32_t*)(ws + OFF_KEY);
    uint8_t*  g    = ws + OFF_G;
    uint32_t* selc = (uint32_t*)(ws + OFF_SELC);

    float* outSparse = (float*)d_out;
    float* outSel    = outSparse + (size_t)B_ * C_ALL * HW;

    k_zero <<<B_ * HWRD / 4 / 256, 256, 0, stream>>>((uint4*)hist);
    k_prep <<<NPIX / 4 / 256, 256, 0, stream>>>(util, (uint4*)key, (uint32_t*)g, hist);
    k_sel  <<<B_, 1024, 0, stream>>>(key, g, hist, budget, selc, outSel);
    dim3 gridSP(HW / 4 / 256, C_ALL, B_);
    k_sparse<<<gridSP, 256, 0, stream>>>(collab, selc, outSparse);
}